// Round 10
// baseline (81.503 us; speedup 1.0000x reference)
//
#include <hip/hip_runtime.h>
#include <hip/hip_bf16.h>

// ContrastiveLoss (SupCon-style), N=4096 rows, K=256 dim, TEMP=0.5.
// loss = mean over same-label off-diag pairs of [log(neg_i + e_ij) - t2_ij],
//   t2_ij = 2*sim_ij, e_ij = exp(t2_ij), neg_i = sum_{lab_j != lab_i} e_ij.
// e_ij <= e^2 ~ 7.4, neg_i >= ~550 -> log(neg_i+e) = log n + e/n (2nd-order
// dropped, <=1e-4 rel [R7]). Stats symmetric (e_ij=e_ji) -> per-COLUMN sums:
// exsum, pexp, pt2, pcnt; neg = exsum-pexp; loss = S[c log n + pe/n - tt]/S c.
//
// R10: R9 decomposition: negsum ~ 24us FIXED + ~8us transaction-proportional
// (bf16 40us @2x trans vs fp8 32us @1x). The fixed term tracks the PHASE
// STRUCTURE: 4-8 staged rounds/block, each ending in a full-block barrier
// (implicit vmcnt(0)) where all waves jointly eat cross-XCD L3 latency, x4
// block-rounds/CU, nothing to overlap. Fix: fp8 K=256 is only 64KB per
// 128x128 block -> stage ALL of K up front (64 gll16 in flight = max MLP),
// ONE barrier, then uninterrupted ds_read+MFMA+epilogue. 64KB LDS still
// gives 2 blocks/CU so block B's compute overlaps block A's drain.
//
// pk8 layout per 16-row tile (4096 B):
//   byte[u*1024 + quad*256 + r16*16 + h*8 + j] = fp8(norm8[r16][quad*8+(2u+h)*32+j])
// -> chunk (tile,u) = 1KB = 64 lanes x 16B = one gll16; a lane's 16B = its
// K=32 fragments for c-steps {2u, 2u+1} (k_local = quad*8 + j).
// C/D: col = lane&15, row = (lane>>4)*4 + reg  [learn_hip m89/m91; R3-R9
// validated end-to-end]. Elements scaled x8 (fp8 subnormal clearance);
// acc = 64*sim -> t2 = acc * 2^-5 exact.
//
// ws: [0,1MB) pk8; [2MB,6MB) part[4][64][4096] f32; [6MB,+16B) acc[4].

#define N_ROWS 4096
#define K_DIM  256

typedef __attribute__((ext_vector_type(4))) float float4v;    // MFMA C/D
typedef __attribute__((ext_vector_type(4))) float f4;
typedef __attribute__((ext_vector_type(4))) int   int4v;
typedef __attribute__((ext_vector_type(2))) long  long2v;     // 2 x 8B frags

#define PK_OFF    0
#define PART_OFF  (2 * 1024 * 1024)
#define ACC_OFF   (PART_OFF + 4 * 64 * N_ROWS * 4)     // +4 MB

// async global->LDS, 16B/lane: dest = wave-uniform base + lane*16 [m97 path]
__device__ __forceinline__ void gll16(const void* g, void* l) {
    __builtin_amdgcn_global_load_lds(
        (const __attribute__((address_space(1))) unsigned int*)g,
        (__attribute__((address_space(3))) unsigned int*)l, 16, 0, 0);
}

// ---------------------------------------------------------------------------
// K1: block = one 16-row tile. Coalesced float4 loads -> LDS, per-row norms
// via 16-lane shuffle groups, x8-scaled fp8 pack, 16B/thread coalesced store.
__global__ void normalize_kernel(const float* __restrict__ emb,
                                 unsigned char* __restrict__ pk8,
                                 float* __restrict__ acc) {
    int tile = blockIdx.x, t = threadIdx.x;
    __shared__ float lds[16 * 256];
    __shared__ float sc[16];
    const f4* src = (const f4*)(emb + tile * 16 * 256);
    f4* dst4 = (f4*)lds;
    #pragma unroll
    for (int it = 0; it < 4; ++it) dst4[t + 256 * it] = src[t + 256 * it];
    __syncthreads();
    int wave = t >> 6, lane = t & 63;
    int row = wave * 4 + (lane >> 4);          // 4 rows per wave
    float s = 0.f;
    #pragma unroll
    for (int m = 0; m < 16; ++m) {
        float x = lds[row * 256 + (lane & 15) + 16 * m];
        s += x * x;
    }
    s += __shfl_xor(s, 1); s += __shfl_xor(s, 2);
    s += __shfl_xor(s, 4); s += __shfl_xor(s, 8);
    float scale = 1.0f / fmaxf(sqrtf(s), 1e-12f);
    if ((lane & 15) == 0) sc[row] = scale;
    __syncthreads();
    // pack 16 bytes: fixed (u, quad, r16) per thread; h,j sweep the 16B
    int u = t >> 6, quad = (t >> 4) & 3, r16 = t & 15;
    float s8 = sc[r16] * 8.0f;
    const float* lr = lds + r16 * 256;
    int4v wv;
    #pragma unroll
    for (int wi = 0; wi < 4; ++wi) {           // word wi = bytes 4wi..4wi+3
        int h  = wi >> 1;
        int j0 = (wi & 1) * 4;
        int kb = quad * 8 + (2 * u + h) * 32 + j0;
        float v0 = lr[kb + 0] * s8, v1 = lr[kb + 1] * s8;
        float v2 = lr[kb + 2] * s8, v3 = lr[kb + 3] * s8;
        int wd = __builtin_amdgcn_cvt_pk_fp8_f32(v0, v1, 0, 0);
        wd     = __builtin_amdgcn_cvt_pk_fp8_f32(v2, v3, wd, 1);
        wv[wi] = wd;
    }
    *(int4v*)(pk8 + tile * 4096 + t * 16) = wv;
    if (tile == 0 && t < 4) acc[t] = 0.0f;     // loss, cnt, ticket, pad
}

// ---------------------------------------------------------------------------
// K2: fp8 fused sim/exp/stats, SINGLE-PHASE. Grid 1024 = 32x32 blocktiles of
// 128x128. 4 waves in 2x2, each a 64x64 subtile (4x4 MFMA frags). Full K=256
// staged up front: A-panel 32KB + B-panel 32KB = 64 chunks of 1KB, 16 gll16
// per wave, ONE __syncthreads, then 32 ds_read_b128 + 128 MFMA per wave with
// no further barriers. 64KB LDS -> 2 blocks/CU for cross-block overlap.
// Epilogue: per-column stats, 2 shuffles/stat, contention-free partials.
__global__ __launch_bounds__(256, 2)
void negsum_kernel(const unsigned char* __restrict__ pk8,
                   const int* __restrict__ labels,
                   float* __restrict__ part) {
    __shared__ __align__(16) unsigned char As8[32768];   // 8 tiles x 4 chunks
    __shared__ __align__(16) unsigned char Bs8[32768];
    int t = threadIdx.x;
    int w = t >> 6, lane = t & 63;
    int lane16 = lane & 15, quad = lane >> 4;
    int bi = blockIdx.x >> 5, bj = blockIdx.x & 31;
    int wi = w >> 1, wj = w & 1;

    int ibase = bi * 128 + wi * 64;
    int jbase = bj * 128 + wj * 64;
    int labi[16], labj[4];
    #pragma unroll
    for (int it = 0; it < 4; ++it)
        #pragma unroll
        for (int r = 0; r < 4; ++r)
            labi[it * 4 + r] = labels[ibase + it * 16 + quad * 4 + r];
    #pragma unroll
    for (int jt = 0; jt < 4; ++jt)
        labj[jt] = labels[jbase + jt * 16 + lane16];

    const char* pkb = (const char*)pk8;        // tile16 = 4KB, chunk(u) = 1KB

    // ---- stage ALL of K: waves 0-1 -> A (tiles bi*8..+8), 2-3 -> B ----
    {
        int isA   = (w < 2);
        int wloc  = isA ? w : (w - 2);
        int btile = isA ? bi : bj;
        unsigned char* panel = isA ? As8 : Bs8;
        #pragma unroll
        for (int u = 0; u < 16; ++u) {         // 4 tiles x 4 chunks per wave
            int tl = wloc * 4 + (u >> 2), cs = u & 3;
            gll16(pkb + (((btile * 8 + tl) << 12) | (cs << 10)) + lane * 16,
                  panel + (((tl << 2) | cs) << 10));
        }
    }

    float4v acc[4][4];
    #pragma unroll
    for (int a = 0; a < 4; ++a)
        #pragma unroll
        for (int b = 0; b < 4; ++b)
            acc[a][b] = (float4v){0.f, 0.f, 0.f, 0.f};

    __syncthreads();                           // single drain of all 64 loads

    #pragma unroll
    for (int cs = 0; cs < 4; ++cs) {
        long2v av[4], bv[4];
        #pragma unroll
        for (int it = 0; it < 4; ++it)
            av[it] = *(const long2v*)(As8 + (((((wi * 4 + it) << 2) | cs) << 10)) + lane * 16);
        #pragma unroll
        for (int jt = 0; jt < 4; ++jt)
            bv[jt] = *(const long2v*)(Bs8 + (((((wj * 4 + jt) << 2) | cs) << 10)) + lane * 16);
        #pragma unroll
        for (int h = 0; h < 2; ++h)
            #pragma unroll
            for (int it = 0; it < 4; ++it)
                #pragma unroll
                for (int jt = 0; jt < 4; ++jt)
                    acc[it][jt] = __builtin_amdgcn_mfma_f32_16x16x32_fp8_fp8(
                        av[it][h], bv[jt][h], acc[it][jt], 0, 0, 0);
    }

    // epilogue: per-column stats (== per-row by symmetry); acc = 64*sim
    float ex[4] = {0,0,0,0}, pe[4] = {0,0,0,0};
    float tt[4] = {0,0,0,0}, pc[4] = {0,0,0,0};
    #pragma unroll
    for (int it = 0; it < 4; ++it) {
        #pragma unroll
        for (int jt = 0; jt < 4; ++jt) {
            int j = jbase + jt * 16 + lane16;
            #pragma unroll
            for (int r = 0; r < 4; ++r) {
                int i = ibase + it * 16 + quad * 4 + r;
                float t2 = acc[it][jt][r] * 0.03125f;   // 2*sim, exact pow2
                float e  = __expf(t2);
                bool keep = (i != j);
                bool same = (labi[it * 4 + r] == labj[jt]);
                ex[jt] += keep ? e : 0.0f;
                float m = (same && keep) ? 1.0f : 0.0f;
                pe[jt] = fmaf(m, e,  pe[jt]);
                tt[jt] = fmaf(m, t2, tt[jt]);
                pc[jt] += m;
            }
        }
    }
    int i64 = bi * 2 + wi;                     // this wave's 64-row chunk
    #pragma unroll
    for (int jt = 0; jt < 4; ++jt) {
        float v0 = ex[jt], v1 = pe[jt], v2 = tt[jt], v3 = pc[jt];
        v0 += __shfl_xor(v0, 16); v0 += __shfl_xor(v0, 32);
        v1 += __shfl_xor(v1, 16); v1 += __shfl_xor(v1, 32);
        v2 += __shfl_xor(v2, 16); v2 += __shfl_xor(v2, 32);
        v3 += __shfl_xor(v3, 16); v3 += __shfl_xor(v3, 32);
        if (quad == 0) {
            int col = jbase + jt * 16 + lane16;
            part[((0 * 64 + i64) << 12) + col] = v0;
            part[((1 * 64 + i64) << 12) + col] = v1;
            part[((2 * 64 + i64) << 12) + col] = v2;
            part[((3 * 64 + i64) << 12) + col] = v3;
        }
    }
}

// ---------------------------------------------------------------------------
// K3: per column j: sum 64 partials, closed-form loss, block reduce, 2 scalar
// atomics; LAST block (device-fence ticket) computes the final division.
__global__ void rowreduce_kernel(const float* __restrict__ part,
                                 float* __restrict__ acc,
                                 float* __restrict__ out) {
    int j = blockIdx.x * 256 + threadIdx.x;
    float ex = 0.f, pe = 0.f, tt = 0.f, pc = 0.f;
    for (int ch = 0; ch < 64; ++ch) {
        ex += part[((0 * 64 + ch) << 12) + j];
        pe += part[((1 * 64 + ch) << 12) + j];
        tt += part[((2 * 64 + ch) << 12) + j];
        pc += part[((3 * 64 + ch) << 12) + j];
    }
    float lsum = 0.f;
    if (pc > 0.f) {
        float n = ex - pe;                      // negative-pair sum
        lsum = pc * logf(n) + pe / n - tt;
    } else {
        pc = 0.f;
    }
    #pragma unroll
    for (int off = 32; off > 0; off >>= 1) {
        lsum += __shfl_down(lsum, off, 64);
        pc   += __shfl_down(pc,   off, 64);
    }
    __shared__ float sl[4], sc2[4];
    int wave = threadIdx.x >> 6, lane = threadIdx.x & 63;
    if (lane == 0) { sl[wave] = lsum; sc2[wave] = pc; }
    __syncthreads();
    if (threadIdx.x == 0) {
        atomicAdd(&acc[0], sl[0] + sl[1] + sl[2] + sl[3]);
        atomicAdd(&acc[1], sc2[0] + sc2[1] + sc2[2] + sc2[3]);
        __threadfence();
        int ticket = atomicAdd((int*)(acc + 2), 1);
        if (ticket == 15) {
            float ls = atomicAdd(&acc[0], 0.0f);
            float cs = atomicAdd(&acc[1], 0.0f);
            out[0] = ls / cs;
        }
    }
}

// ---------------------------------------------------------------------------
extern "C" void kernel_launch(void* const* d_in, const int* in_sizes, int n_in,
                              void* d_out, int out_size, void* d_ws, size_t ws_size,
                              hipStream_t stream) {
    const float* emb    = (const float*)d_in[0];
    const int*   labels = (const int*)d_in[1];
    float* out = (float*)d_out;
    char*  ws  = (char*)d_ws;

    unsigned char* pk8  = (unsigned char*)(ws + PK_OFF);
    float*         part = (float*)(ws + PART_OFF);
    float*         acc  = (float*)(ws + ACC_OFF);

    normalize_kernel<<<N_ROWS / 16, 256, 0, stream>>>(emb, pk8, acc);
    negsum_kernel<<<1024, 256, 0, stream>>>(pk8, labels, part);
    rowreduce_kernel<<<16, 256, 0, stream>>>(part, acc, out);
}